// Round 8
// baseline (217.615 us; speedup 1.0000x reference)
//
#include <hip/hip_runtime.h>
#include <hip/hip_bf16.h>

#define SEQ   2048
#define DM    1024
#define NH    16
#define DH    64
#define MAXD  128

typedef __attribute__((ext_vector_type(8))) short  short8;   // 8 bf16 = 4 VGPRs
typedef __attribute__((ext_vector_type(4))) float  float4v;  // MFMA 16x16 accumulator

__device__ __forceinline__ short8 ld8(const void* p) {
    short8 v; __builtin_memcpy(&v, p, 16); return v;
}
__device__ __forceinline__ void st8(void* p, short8 v) {
    __builtin_memcpy(p, &v, 16);
}
__device__ __forceinline__ short bf16bits(float f) {
    __hip_bfloat16 b = __float2bfloat16(f);
    short s; __builtin_memcpy(&s, &b, 2); return s;
}
__device__ __forceinline__ __hip_bfloat16 tobf(float f) { return __float2bfloat16(f); }
__device__ __forceinline__ __hip_bfloat16 tobf(__hip_bfloat16 b) { return b; }

// async global->LDS, 16 B per lane. lds = WAVE-UNIFORM base (HW adds lane*16).
__device__ __forceinline__ void async16(void* lds, const void* g) {
    __builtin_amdgcn_global_load_lds(
        (const __attribute__((address_space(1))) unsigned int*)g,
        (__attribute__((address_space(3))) unsigned int*)lds, 16, 0, 0);
}

// ---------------------------------------------------------------------------
// fp32 -> bf16 elementwise convert (8 elems/thread).
// ---------------------------------------------------------------------------
__global__ __launch_bounds__(256) void cvt_f32_bf16(
    const float* __restrict__ src, __hip_bfloat16* __restrict__ dst) {
    const size_t i = ((size_t)blockIdx.x * 256 + threadIdx.x) * 8;
    float f[8]; __builtin_memcpy(f, src + i, 32);
    short8 v;
#pragma unroll
    for (int j = 0; j < 8; ++j) v[j] = bf16bits(f[j]);
    st8(dst + i, v);
}

// ---------------------------------------------------------------------------
// Tiled transpose with bf16 output: dst[c][r] = bf16(src[r][c]).
// ---------------------------------------------------------------------------
template <typename TS>
__global__ __launch_bounds__(256) void transpose_to_bf16(
    const TS* __restrict__ src, __hip_bfloat16* __restrict__ dst,
    int s_stride, int d_stride) {
    __shared__ __hip_bfloat16 tile[32][33];
    const int t = threadIdx.x;
    const int tx = t % 32, ty = t / 32;           // ty 0..7
    const int c0 = blockIdx.x * 32, r0 = blockIdx.y * 32;
#pragma unroll
    for (int i = 0; i < 4; ++i)
        tile[ty + i * 8][tx] = tobf(src[(size_t)(r0 + ty + i * 8) * s_stride + c0 + tx]);
    __syncthreads();
#pragma unroll
    for (int i = 0; i < 4; ++i)
        dst[(size_t)(c0 + ty + i * 8) * d_stride + r0 + tx] = tile[tx][ty + i * 8];
}

// ---------------------------------------------------------------------------
// bf16 MFMA GEMM, m97 structure: 128x128x32 tiles, 4 waves, global_load_lds
// width-16 staging into unpadded 64-B rows. C = A[M,K] * BT[N,K]^T.
// ---------------------------------------------------------------------------
template <typename TC>
__global__ __launch_bounds__(256) void gemm_mfma(
    const __hip_bfloat16* __restrict__ A,
    const __hip_bfloat16* __restrict__ BT,
    TC* __restrict__ C,
    int M, int N, int K) {
    __shared__ short As[128 * 32];   // [m][k], 64-B rows (no pad: async layout)
    __shared__ short Bs[128 * 32];   // [n][k]

    const int t = threadIdx.x;
    const int w = t >> 6, lane = t & 63;
    const int l15 = lane & 15, quad = lane >> 4;
    const int row0 = blockIdx.y * 128;
    const int col0 = blockIdx.x * 128;
    const int wm = w >> 1, wn = w & 1;

    float4v acc[4][4];
#pragma unroll
    for (int i = 0; i < 4; ++i)
#pragma unroll
        for (int j = 0; j < 4; ++j) acc[i][j] = (float4v){0.f, 0.f, 0.f, 0.f};

    const int mloc0 = lane >> 2;       // row-within-chunk
    const int u     = lane & 3;        // 16-B unit within 64-B row

    for (int k0 = 0; k0 < K; k0 += 32) {
#pragma unroll
        for (int i = 0; i < 2; ++i) {
            const int c    = 2 * w + i;          // chunk 0..7 (16 rows each)
            const int mloc = c * 16 + mloc0;
            async16(&As[c * 512], A  + (size_t)(row0 + mloc) * K + k0 + u * 8);
            async16(&Bs[c * 512], BT + (size_t)(col0 + mloc) * K + k0 + u * 8);
        }
        __syncthreads();

        short8 af[4], bf[4];
#pragma unroll
        for (int mt = 0; mt < 4; ++mt)
            af[mt] = ld8(&As[(wm * 64 + mt * 16 + l15) * 32 + quad * 8]);
#pragma unroll
        for (int nt = 0; nt < 4; ++nt)
            bf[nt] = ld8(&Bs[(wn * 64 + nt * 16 + l15) * 32 + quad * 8]);
#pragma unroll
        for (int mt = 0; mt < 4; ++mt)
#pragma unroll
            for (int nt = 0; nt < 4; ++nt)
                acc[mt][nt] = __builtin_amdgcn_mfma_f32_16x16x32_bf16(
                    af[mt], bf[nt], acc[mt][nt], 0, 0, 0);
        __syncthreads();
    }

#pragma unroll
    for (int mt = 0; mt < 4; ++mt)
#pragma unroll
        for (int nt = 0; nt < 4; ++nt)
#pragma unroll
            for (int r = 0; r < 4; ++r) {
                const int row = row0 + wm * 64 + mt * 16 + quad * 4 + r;
                const int col = col0 + wn * 64 + nt * 16 + l15;
                float v = acc[mt][nt][r];
                if constexpr (__is_same(TC, float)) C[(size_t)row * N + col] = v;
                else C[(size_t)row * N + col] = __float2bfloat16(v);
            }
}

// ---------------------------------------------------------------------------
// MFMA flash attention, double-buffered K/V, conflict-free stride 68.
// grid (SEQ/64, NH), 4 waves; wave w owns queries q0+w*16..+15.
// ---------------------------------------------------------------------------
#define KSTR 68   // LDS row stride in shorts (34 dwords: balanced b128 banks)

__global__ __launch_bounds__(256) void attn_mfma(
    const __hip_bfloat16* __restrict__ qkv,
    const __hip_bfloat16* __restrict__ vT,
    const float* __restrict__ rel_bias,
    __hip_bfloat16* __restrict__ attnb) {
    __shared__ short Kt[2][64 * KSTR];
    __shared__ short Vt[2][64 * KSTR];
    __shared__ short Pl[4 * 16 * KSTR];
    __shared__ float biasL[MAXD];

    const int t = threadIdx.x;
    const int w = t >> 6, lane = t & 63;
    const int l15 = lane & 15, quad = lane >> 4;
    const int h  = blockIdx.y;
    const int q0 = blockIdx.x * 64;
    const int qw = q0 + w * 16;

    if (t < MAXD) biasL[t] = rel_bias[t * NH + h];

    // persistent Q fragments (A-layout): Q[q=l15][d = c*32 + quad*8 + j]
    short8 qf[2];
#pragma unroll
    for (int c = 0; c < 2; ++c)
        qf[c] = ld8(qkv + (size_t)(qw + l15) * (3 * DM) + h * DH + c * 32 + quad * 8);

    float4v o_acc[4];
#pragma unroll
    for (int nt = 0; nt < 4; ++nt) o_acc[nt] = (float4v){0.f, 0.f, 0.f, 0.f};
    float m_i[4], l_i[4];
#pragma unroll
    for (int r = 0; r < 4; ++r) { m_i[r] = -1e30f; l_i[r] = 0.f; }

    // staging map: 512 16-B units per matrix, 2 per thread
    short8 kreg[2], vreg[2];
    auto load_tile = [&](int k0) {
#pragma unroll
        for (int p = 0; p < 2; ++p) {
            const int idx = p * 256 + t;
            const int row = idx >> 3, u = idx & 7;
            kreg[p] = ld8(qkv + (size_t)(k0 + row) * (3 * DM) + DM + h * DH + u * 8);
            vreg[p] = ld8(vT + (size_t)(h * DH + row) * SEQ + k0 + u * 8);
        }
    };
    auto store_tile = [&](int buf) {
#pragma unroll
        for (int p = 0; p < 2; ++p) {
            const int idx = p * 256 + t;
            const int row = idx >> 3, u = idx & 7;
            st8(&Kt[buf][row * KSTR + u * 8], kreg[p]);
            st8(&Vt[buf][row * KSTR + u * 8], vreg[p]);
        }
    };

    load_tile(0);
    store_tile(0);
    __syncthreads();

    for (int kb = 0; kb < SEQ / 64; ++kb) {
        const int cur = kb & 1;
        const int k0  = kb * 64;
        if (kb < SEQ / 64 - 1) load_tile(k0 + 64);   // prefetch (global latency hides)

        // S = Q K^T  (16q x 64keys per wave)
        float4v s_acc[4];
#pragma unroll
        for (int kt = 0; kt < 4; ++kt) s_acc[kt] = (float4v){0.f, 0.f, 0.f, 0.f};
#pragma unroll
        for (int c = 0; c < 2; ++c)
#pragma unroll
            for (int kt = 0; kt < 4; ++kt) {
                const int key = kt * 16 + l15;
                short8 kf = ld8(&Kt[cur][key * KSTR + (c * 4 + quad) * 8]);
                s_acc[kt] = __builtin_amdgcn_mfma_f32_16x16x32_bf16(qf[c], kf, s_acc[kt], 0, 0, 0);
            }

        // scale + relative bias
        float sv[4][4];
#pragma unroll
        for (int kt = 0; kt < 4; ++kt)
#pragma unroll
            for (int r = 0; r < 4; ++r) {
                const int kg = k0 + kt * 16 + l15;
                const int qg = qw + quad * 4 + r;
                int rel = kg - qg; if (rel < 0) rel = -rel;
                if (rel > MAXD - 1) rel = MAXD - 1;
                sv[kt][r] = s_acc[kt][r] * 0.125f + biasL[rel];
            }

        // online softmax (rows across 16 lanes of each quad)
        float rowm[4];
#pragma unroll
        for (int r = 0; r < 4; ++r)
            rowm[r] = fmaxf(fmaxf(sv[0][r], sv[1][r]), fmaxf(sv[2][r], sv[3][r]));
#pragma unroll
        for (int d = 1; d < 16; d <<= 1)
#pragma unroll
            for (int r = 0; r < 4; ++r) rowm[r] = fmaxf(rowm[r], __shfl_xor(rowm[r], d));

        float al[4], rs[4];
#pragma unroll
        for (int r = 0; r < 4; ++r) {
            const float mn = fmaxf(m_i[r], rowm[r]);
            al[r] = __expf(m_i[r] - mn);
            m_i[r] = mn;
            rs[r] = 0.f;
        }
#pragma unroll
        for (int kt = 0; kt < 4; ++kt)
#pragma unroll
            for (int r = 0; r < 4; ++r) {
                const float p = __expf(sv[kt][r] - m_i[r]);
                sv[kt][r] = p;
                rs[r] += p;
            }
#pragma unroll
        for (int d = 1; d < 16; d <<= 1)
#pragma unroll
            for (int r = 0; r < 4; ++r) rs[r] += __shfl_xor(rs[r], d);
#pragma unroll
        for (int r = 0; r < 4; ++r) l_i[r] = l_i[r] * al[r] + rs[r];
#pragma unroll
        for (int nt = 0; nt < 4; ++nt)
#pragma unroll
            for (int r = 0; r < 4; ++r) o_acc[nt][r] *= al[r];

        // P -> per-wave LDS ([q][key], stride KSTR)
#pragma unroll
        for (int kt = 0; kt < 4; ++kt)
#pragma unroll
            for (int r = 0; r < 4; ++r)
                Pl[w * 16 * KSTR + (quad * 4 + r) * KSTR + kt * 16 + l15] = bf16bits(sv[kt][r]);

        // O += P V
#pragma unroll
        for (int kc = 0; kc < 2; ++kc) {
            short8 pf = ld8(&Pl[w * 16 * KSTR + l15 * KSTR + kc * 32 + quad * 8]);
#pragma unroll
            for (int nt = 0; nt < 4; ++nt) {
                const int d = nt * 16 + l15;
                short8 vf = ld8(&Vt[cur][d * KSTR + (kc * 4 + quad) * 8]);
                o_acc[nt] = __builtin_amdgcn_mfma_f32_16x16x32_bf16(pf, vf, o_acc[nt], 0, 0, 0);
            }
        }

        if (kb < SEQ / 64 - 1) store_tile(cur ^ 1);  // fill next buffer
        __syncthreads();                             // one barrier per tile
    }

    // normalize + store
#pragma unroll
    for (int nt = 0; nt < 4; ++nt)
#pragma unroll
        for (int r = 0; r < 4; ++r) {
            const int row = qw + quad * 4 + r;
            const int col = h * DH + nt * 16 + l15;
            attnb[(size_t)row * DM + col] = __float2bfloat16(o_acc[nt][r] / l_i[r]);
        }
}

extern "C" void kernel_launch(void* const* d_in, const int* in_sizes, int n_in,
                              void* d_out, int out_size, void* d_ws, size_t ws_size,
                              hipStream_t stream) {
    const float* x        = (const float*)d_in[0];   // [2048][1024] fp32
    const float* w_qkv    = (const float*)d_in[1];   // [1024][3072] fp32
    const float* w_out    = (const float*)d_in[2];   // [1024][1024] fp32
    const float* rel_bias = (const float*)d_in[3];   // [128][16]    fp32
    float* out = (float*)d_out;                      // [2048][1024] fp32

    // ws layout (16-B aligned)
    char* p = (char*)d_ws;
    __hip_bfloat16* xb    = (__hip_bfloat16*)p;  p += (size_t)SEQ * DM * 2;      // 4 MB
    __hip_bfloat16* wqT   = (__hip_bfloat16*)p;  p += (size_t)3 * DM * DM * 2;   // 6 MB
    __hip_bfloat16* woT   = (__hip_bfloat16*)p;  p += (size_t)DM * DM * 2;       // 2 MB
    __hip_bfloat16* qkvb  = (__hip_bfloat16*)p;  p += (size_t)SEQ * 3 * DM * 2;  // 12 MB
    __hip_bfloat16* vT    = (__hip_bfloat16*)p;  p += (size_t)DM * SEQ * 2;      // 4 MB
    __hip_bfloat16* attnb = (__hip_bfloat16*)p;                                  // 4 MB

    // x -> bf16
    cvt_f32_bf16<<<SEQ * DM / (256 * 8), 256, 0, stream>>>(x, xb);

    // weight transposes (fp32 -> bf16)
    transpose_to_bf16<float><<<dim3(3 * DM / 32, DM / 32), 256, 0, stream>>>(
        w_qkv, wqT, 3 * DM, DM);
    transpose_to_bf16<float><<<dim3(DM / 32, DM / 32), 256, 0, stream>>>(
        w_out, woT, DM, DM);

    // 1) qkv = x @ w_qkv
    gemm_mfma<__hip_bfloat16><<<dim3(3 * DM / 128, SEQ / 128), 256, 0, stream>>>(
        xb, wqT, qkvb, SEQ, 3 * DM, DM);

    // V^T for attention B-frags
    transpose_to_bf16<__hip_bfloat16><<<dim3(DM / 32, SEQ / 32), 256, 0, stream>>>(
        qkvb + 2 * DM, vT, 3 * DM, SEQ);

    // 2) attention
    attn_mfma<<<dim3(SEQ / 64, NH), 256, 0, stream>>>(qkvb, vT, rel_bias, attnb);

    // 3) out = attn @ w_out (fp32 out)
    gemm_mfma<float><<<dim3(DM / 128, SEQ / 128), 256, 0, stream>>>(
        attnb, woT, out, SEQ, DM, DM);
}

// Round 9
// 177.667 us; speedup vs baseline: 1.2248x; 1.2248x over previous
//
#include <hip/hip_runtime.h>
#include <hip/hip_bf16.h>

#define SEQ   2048
#define DM    1024
#define NH    16
#define DH    64
#define MAXD  128

typedef __attribute__((ext_vector_type(8))) short  short8;   // 8 bf16 = 4 VGPRs
typedef __attribute__((ext_vector_type(4))) float  float4v;  // MFMA 16x16 accumulator

__device__ __forceinline__ short8 ld8(const void* p) {
    short8 v; __builtin_memcpy(&v, p, 16); return v;
}
__device__ __forceinline__ void st8(void* p, short8 v) {
    __builtin_memcpy(p, &v, 16);
}
__device__ __forceinline__ short bf16bits(float f) {
    __hip_bfloat16 b = __float2bfloat16(f);
    short s; __builtin_memcpy(&s, &b, 2); return s;
}
__device__ __forceinline__ float bits2f(short s) {
    unsigned u = (unsigned)(unsigned short)s << 16;
    return __builtin_bit_cast(float, u);
}

// async global->LDS, 16 B per lane. lds = WAVE-UNIFORM base (HW adds lane*16).
__device__ __forceinline__ void async16(void* lds, const void* g) {
    __builtin_amdgcn_global_load_lds(
        (const __attribute__((address_space(1))) unsigned int*)g,
        (__attribute__((address_space(3))) unsigned int*)lds, 16, 0, 0);
}

// DPP cross-lane (16-lane group) reductions — VALU-latency, no LDS pipe.
template <int CTRL>
__device__ __forceinline__ float dppmov(float x) {
    return __builtin_bit_cast(float,
        __builtin_amdgcn_update_dpp(0, __builtin_bit_cast(int, x), CTRL, 0xf, 0xf, true));
}
__device__ __forceinline__ float red16max(float x) {
    x = fmaxf(x, dppmov<0xB1>(x));   // quad_perm xor1
    x = fmaxf(x, dppmov<0x4E>(x));   // quad_perm xor2
    x = fmaxf(x, dppmov<0x141>(x));  // row_half_mirror (combines quad pairs)
    x = fmaxf(x, dppmov<0x140>(x));  // row_mirror (combines halves)
    return x;
}
__device__ __forceinline__ float red16sum(float x) {
    x += dppmov<0xB1>(x);
    x += dppmov<0x4E>(x);
    x += dppmov<0x141>(x);
    x += dppmov<0x140>(x);
    return x;
}

// ---------------------------------------------------------------------------
// fp32 -> bf16 elementwise convert (8 elems/thread).
// ---------------------------------------------------------------------------
__global__ __launch_bounds__(256) void cvt_f32_bf16(
    const float* __restrict__ src, __hip_bfloat16* __restrict__ dst) {
    const size_t i = ((size_t)blockIdx.x * 256 + threadIdx.x) * 8;
    float f[8]; __builtin_memcpy(f, src + i, 32);
    short8 v;
#pragma unroll
    for (int j = 0; j < 8; ++j) v[j] = bf16bits(f[j]);
    st8(dst + i, v);
}

// ---------------------------------------------------------------------------
// Fused weight transposes: wq [1024][3072] -> wqT [3072][1024] (blocks x<96),
// wo [1024][1024] -> woT [1024][1024] (blocks x>=96). fp32 -> bf16.
// ---------------------------------------------------------------------------
__global__ __launch_bounds__(256) void transpose_weights(
    const float* __restrict__ wq, const float* __restrict__ wo,
    __hip_bfloat16* __restrict__ wqT, __hip_bfloat16* __restrict__ woT) {
    __shared__ __hip_bfloat16 tile[32][33];
    const int t = threadIdx.x;
    const int tx = t % 32, ty = t / 32;
    const int bx = blockIdx.x, r0 = blockIdx.y * 32;
    const float* src; __hip_bfloat16* dst; int ss, ds, c0;
    if (bx < 96) { src = wq; dst = wqT; ss = 3 * DM; ds = DM; c0 = bx * 32; }
    else         { src = wo; dst = woT; ss = DM;     ds = DM; c0 = (bx - 96) * 32; }
#pragma unroll
    for (int i = 0; i < 4; ++i)
        tile[ty + i * 8][tx] = __float2bfloat16(src[(size_t)(r0 + ty + i * 8) * ss + c0 + tx]);
    __syncthreads();
#pragma unroll
    for (int i = 0; i < 4; ++i)
        dst[(size_t)(c0 + ty + i * 8) * ds + r0 + tx] = tile[tx][ty + i * 8];
}

// ---------------------------------------------------------------------------
// bf16 -> bf16 tiled transpose (for V^T).
// ---------------------------------------------------------------------------
__global__ __launch_bounds__(256) void transpose_v(
    const __hip_bfloat16* __restrict__ src, __hip_bfloat16* __restrict__ dst,
    int s_stride, int d_stride) {
    __shared__ __hip_bfloat16 tile[32][33];
    const int t = threadIdx.x;
    const int tx = t % 32, ty = t / 32;
    const int c0 = blockIdx.x * 32, r0 = blockIdx.y * 32;
#pragma unroll
    for (int i = 0; i < 4; ++i)
        tile[ty + i * 8][tx] = src[(size_t)(r0 + ty + i * 8) * s_stride + c0 + tx];
    __syncthreads();
#pragma unroll
    for (int i = 0; i < 4; ++i)
        dst[(size_t)(c0 + ty + i * 8) * d_stride + r0 + tx] = tile[tx][ty + i * 8];
}

// ---------------------------------------------------------------------------
// bf16 MFMA GEMM, m97 structure: 128x(32*NT)x32 tiles, 4 waves (2x2),
// global_load_lds width-16 staging. C = A[M,K] * BT[N,K]^T.
// NT=4 -> 128x128 tile; NT=2 -> 128x64 tile (for small-N GEMMs).
// ---------------------------------------------------------------------------
template <int NT, typename TC>
__global__ __launch_bounds__(256) void gemm_mfma(
    const __hip_bfloat16* __restrict__ A,
    const __hip_bfloat16* __restrict__ BT,
    TC* __restrict__ C,
    int M, int N, int K) {
    __shared__ short As[128 * 32];
    __shared__ short Bs[32 * NT * 32];

    const int t = threadIdx.x;
    const int w = t >> 6, lane = t & 63;
    const int l15 = lane & 15, quad = lane >> 4;
    const int row0 = blockIdx.y * 128;
    const int col0 = blockIdx.x * (32 * NT);
    const int wm = w >> 1, wn = w & 1;

    float4v acc[4][NT];
#pragma unroll
    for (int i = 0; i < 4; ++i)
#pragma unroll
        for (int j = 0; j < NT; ++j) acc[i][j] = (float4v){0.f, 0.f, 0.f, 0.f};

    const int mloc0 = lane >> 2;       // row-within-chunk
    const int u     = lane & 3;        // 16-B unit within 64-B row

    for (int k0 = 0; k0 < K; k0 += 32) {
#pragma unroll
        for (int i = 0; i < 2; ++i) {
            const int c = 2 * w + i;           // chunk 0..7 (16 rows each)
            async16(&As[c * 512], A + (size_t)(row0 + c * 16 + mloc0) * K + k0 + u * 8);
        }
#pragma unroll
        for (int i = 0; i < NT / 2; ++i) {
            const int c = (NT / 2) * w + i;    // chunk 0..2*NT-1
            async16(&Bs[c * 512], BT + (size_t)(col0 + c * 16 + mloc0) * K + k0 + u * 8);
        }
        __syncthreads();

        short8 af[4], bf[NT];
#pragma unroll
        for (int mt = 0; mt < 4; ++mt)
            af[mt] = ld8(&As[(wm * 64 + mt * 16 + l15) * 32 + quad * 8]);
#pragma unroll
        for (int nt = 0; nt < NT; ++nt)
            bf[nt] = ld8(&Bs[(wn * 16 * NT + nt * 16 + l15) * 32 + quad * 8]);
#pragma unroll
        for (int mt = 0; mt < 4; ++mt)
#pragma unroll
            for (int nt = 0; nt < NT; ++nt)
                acc[mt][nt] = __builtin_amdgcn_mfma_f32_16x16x32_bf16(
                    af[mt], bf[nt], acc[mt][nt], 0, 0, 0);
        __syncthreads();
    }

#pragma unroll
    for (int mt = 0; mt < 4; ++mt)
#pragma unroll
        for (int nt = 0; nt < NT; ++nt)
#pragma unroll
            for (int r = 0; r < 4; ++r) {
                const int row = row0 + wm * 64 + mt * 16 + quad * 4 + r;
                const int col = col0 + wn * 16 * NT + nt * 16 + l15;
                float v = acc[mt][nt][r];
                if constexpr (__is_same(TC, float)) C[(size_t)row * N + col] = v;
                else C[(size_t)row * N + col] = __float2bfloat16(v);
            }
}

// ---------------------------------------------------------------------------
// MFMA flash attention, 128-key tiles, DPP softmax, uniform-bias fast path.
// grid (SEQ/64, NH), 4 waves; wave w owns queries q0+w*16..+15.
// Q fragments pre-scaled by exact 0.125 (lossless exponent shift in bf16).
// ---------------------------------------------------------------------------
#define TK  128   // keys per iteration
#define KS  68    // Kt row stride (shorts)
#define VS  136   // Vt / Pl row stride (shorts)

__global__ __launch_bounds__(256) void attn_mfma(
    const __hip_bfloat16* __restrict__ qkv,
    const __hip_bfloat16* __restrict__ vT,
    const float* __restrict__ rel_bias,
    __hip_bfloat16* __restrict__ attnb) {
    __shared__ short Kt[TK * KS];        // [key][d]
    __shared__ short Vt[DH * VS];        // [d][key]
    __shared__ short Pl[4 * 16 * VS];    // per-wave P [q][key]
    __shared__ float biasL[MAXD];

    const int t = threadIdx.x;
    const int w = t >> 6, lane = t & 63;
    const int l15 = lane & 15, quad = lane >> 4;
    const int h  = blockIdx.y;
    const int q0 = blockIdx.x * 64;
    const int qw = q0 + w * 16;

    if (t < MAXD) biasL[t] = rel_bias[t * NH + h];

    // persistent Q fragments, pre-scaled by 0.125 (exact in bf16)
    short8 qf[2];
#pragma unroll
    for (int c = 0; c < 2; ++c) {
        short8 raw = ld8(qkv + (size_t)(qw + l15) * (3 * DM) + h * DH + c * 32 + quad * 8);
#pragma unroll
        for (int j = 0; j < 8; ++j) qf[c][j] = bf16bits(bits2f(raw[j]) * 0.125f);
    }

    float4v o_acc[4];
#pragma unroll
    for (int nt = 0; nt < 4; ++nt) o_acc[nt] = (float4v){0.f, 0.f, 0.f, 0.f};
    float m_i[4], l_i[4];
#pragma unroll
    for (int r = 0; r < 4; ++r) { m_i[r] = -1e30f; l_i[r] = 0.f; }

    for (int kb = 0; kb < SEQ / TK; ++kb) {
        const int k0 = kb * TK;
        // stage K [key][d]: 1024 16-B units, 4/thread
#pragma unroll
        for (int p = 0; p < 4; ++p) {
            const int idx = p * 256 + t;
            const int row = idx >> 3, u = idx & 7;
            st8(&Kt[row * KS + u * 8],
                ld8(qkv + (size_t)(k0 + row) * (3 * DM) + DM + h * DH + u * 8));
        }
        // stage V [d][key]: 1024 16-B units, 4/thread
#pragma unroll
        for (int p = 0; p < 4; ++p) {
            const int idx = p * 256 + t;
            const int row = idx >> 4, u = idx & 15;
            st8(&Vt[row * VS + u * 8],
                ld8(vT + (size_t)(h * DH + row) * SEQ + k0 + u * 8));
        }
        __syncthreads();

        // S = Q K^T : 8 key-blocks of 16
        float4v s_acc[8];
#pragma unroll
        for (int kt = 0; kt < 8; ++kt) s_acc[kt] = (float4v){0.f, 0.f, 0.f, 0.f};
#pragma unroll
        for (int c = 0; c < 2; ++c)
#pragma unroll
            for (int kt = 0; kt < 8; ++kt) {
                short8 kf = ld8(&Kt[(kt * 16 + l15) * KS + (c * 4 + quad) * 8]);
                s_acc[kt] = __builtin_amdgcn_mfma_f32_16x16x32_bf16(qf[c], kf, s_acc[kt], 0, 0, 0);
            }

        // bias (wave-uniform fast path when the whole tile is at max distance)
        float sv[8][4];
        const int dlo = k0 - (qw + 15);
        const int dhi = qw - (k0 + TK - 1);
        if (dlo >= MAXD - 1 || dhi >= MAXD - 1) {
            const float bu = biasL[MAXD - 1];
#pragma unroll
            for (int kt = 0; kt < 8; ++kt)
#pragma unroll
                for (int r = 0; r < 4; ++r) sv[kt][r] = s_acc[kt][r] + bu;
        } else {
#pragma unroll
            for (int kt = 0; kt < 8; ++kt)
#pragma unroll
                for (int r = 0; r < 4; ++r) {
                    const int kg = k0 + kt * 16 + l15;
                    const int qg = qw + quad * 4 + r;
                    int rel = kg - qg; if (rel < 0) rel = -rel;
                    if (rel > MAXD - 1) rel = MAXD - 1;
                    sv[kt][r] = s_acc[kt][r] + biasL[rel];
                }
        }

        // online softmax (DPP reductions across the 16 lanes of each quad-row)
        float rowm[4];
#pragma unroll
        for (int r = 0; r < 4; ++r) {
            float m = sv[0][r];
#pragma unroll
            for (int kt = 1; kt < 8; ++kt) m = fmaxf(m, sv[kt][r]);
            rowm[r] = red16max(m);
        }

        float al[4], rs[4];
#pragma unroll
        for (int r = 0; r < 4; ++r) {
            const float mn = fmaxf(m_i[r], rowm[r]);
            al[r] = __expf(m_i[r] - mn);
            m_i[r] = mn;
            rs[r] = 0.f;
        }
#pragma unroll
        for (int kt = 0; kt < 8; ++kt)
#pragma unroll
            for (int r = 0; r < 4; ++r) {
                const float p = __expf(sv[kt][r] - m_i[r]);
                sv[kt][r] = p;
                rs[r] += p;
            }
#pragma unroll
        for (int r = 0; r < 4; ++r) {
            rs[r] = red16sum(rs[r]);
            l_i[r] = l_i[r] * al[r] + rs[r];
        }
#pragma unroll
        for (int nt = 0; nt < 4; ++nt)
#pragma unroll
            for (int r = 0; r < 4; ++r) o_acc[nt][r] *= al[r];

        // P -> per-wave LDS ([q][key], stride VS)
#pragma unroll
        for (int kt = 0; kt < 8; ++kt)
#pragma unroll
            for (int r = 0; r < 4; ++r)
                Pl[w * 16 * VS + (quad * 4 + r) * VS + kt * 16 + l15] = bf16bits(sv[kt][r]);

        // O += P V
#pragma unroll
        for (int kc = 0; kc < 4; ++kc) {
            short8 pf = ld8(&Pl[w * 16 * VS + l15 * VS + kc * 32 + quad * 8]);
#pragma unroll
            for (int nt = 0; nt < 4; ++nt) {
                short8 vf = ld8(&Vt[(nt * 16 + l15) * VS + kc * 32 + quad * 8]);
                o_acc[nt] = __builtin_amdgcn_mfma_f32_16x16x32_bf16(pf, vf, o_acc[nt], 0, 0, 0);
            }
        }
        __syncthreads();   // before next tile overwrites Kt/Vt
    }

    // normalize + store
#pragma unroll
    for (int nt = 0; nt < 4; ++nt)
#pragma unroll
        for (int r = 0; r < 4; ++r) {
            const int row = qw + quad * 4 + r;
            const int col = h * DH + nt * 16 + l15;
            attnb[(size_t)row * DM + col] = __float2bfloat16(o_acc[nt][r] / l_i[r]);
        }
}

extern "C" void kernel_launch(void* const* d_in, const int* in_sizes, int n_in,
                              void* d_out, int out_size, void* d_ws, size_t ws_size,
                              hipStream_t stream) {
    const float* x        = (const float*)d_in[0];   // [2048][1024] fp32
    const float* w_qkv    = (const float*)d_in[1];   // [1024][3072] fp32
    const float* w_out    = (const float*)d_in[2];   // [1024][1024] fp32
    const float* rel_bias = (const float*)d_in[3];   // [128][16]    fp32
    float* out = (float*)d_out;                      // [2048][1024] fp32

    // ws layout (16-B aligned)
    char* p = (char*)d_ws;
    __hip_bfloat16* xb    = (__hip_bfloat16*)p;  p += (size_t)SEQ * DM * 2;      // 4 MB
    __hip_bfloat16* wqT   = (__hip_bfloat16*)p;  p += (size_t)3 * DM * DM * 2;   // 6 MB
    __hip_bfloat16* woT   = (__hip_bfloat16*)p;  p += (size_t)DM * DM * 2;       // 2 MB
    __hip_bfloat16* qkvb  = (__hip_bfloat16*)p;  p += (size_t)SEQ * 3 * DM * 2;  // 12 MB
    __hip_bfloat16* vT    = (__hip_bfloat16*)p;  p += (size_t)DM * SEQ * 2;      // 4 MB
    __hip_bfloat16* attnb = (__hip_bfloat16*)p;                                  // 4 MB

    // x -> bf16
    cvt_f32_bf16<<<SEQ * DM / (256 * 8), 256, 0, stream>>>(x, xb);

    // fused weight transposes (fp32 -> bf16)
    transpose_weights<<<dim3(128, 32), 256, 0, stream>>>(w_qkv, w_out, wqT, woT);

    // 1) qkv = x @ w_qkv   (128x128 tiles, 384 blocks)
    gemm_mfma<4, __hip_bfloat16><<<dim3(3 * DM / 128, SEQ / 128), 256, 0, stream>>>(
        xb, wqT, qkvb, SEQ, 3 * DM, DM);

    // V^T for attention B-frags
    transpose_v<<<dim3(DM / 32, SEQ / 32), 256, 0, stream>>>(
        qkvb + 2 * DM, vT, 3 * DM, SEQ);

    // 2) attention
    attn_mfma<<<dim3(SEQ / 64, NH), 256, 0, stream>>>(qkvb, vT, rel_bias, attnb);

    // 3) out = attn @ w_out  (128x64 tiles, 256 blocks = 1/CU)
    gemm_mfma<2, float><<<dim3(DM / 64, SEQ / 128), 256, 0, stream>>>(
        attnb, woT, out, SEQ, DM, DM);
}

// Round 10
// 169.720 us; speedup vs baseline: 1.2822x; 1.0468x over previous
//
#include <hip/hip_runtime.h>
#include <hip/hip_bf16.h>

#define SEQ   2048
#define DM    1024
#define NH    16
#define DH    64
#define MAXD  128

typedef __attribute__((ext_vector_type(8))) short  short8;   // 8 bf16 = 4 VGPRs
typedef __attribute__((ext_vector_type(4))) float  float4v;  // MFMA 16x16 accumulator

__device__ __forceinline__ short8 ld8(const void* p) {
    short8 v; __builtin_memcpy(&v, p, 16); return v;
}
__device__ __forceinline__ void st8(void* p, short8 v) {
    __builtin_memcpy(p, &v, 16);
}
__device__ __forceinline__ short bf16bits(float f) {
    __hip_bfloat16 b = __float2bfloat16(f);
    short s; __builtin_memcpy(&s, &b, 2); return s;
}
__device__ __forceinline__ float bits2f(short s) {
    unsigned u = (unsigned)(unsigned short)s << 16;
    return __builtin_bit_cast(float, u);
}

// async global->LDS, 16 B per lane. lds = WAVE-UNIFORM base (HW adds lane*16).
__device__ __forceinline__ void async16(void* lds, const void* g) {
    __builtin_amdgcn_global_load_lds(
        (const __attribute__((address_space(1))) unsigned int*)g,
        (__attribute__((address_space(3))) unsigned int*)lds, 16, 0, 0);
}

// DPP cross-lane (16-lane group) reductions — VALU-latency, no LDS pipe.
template <int CTRL>
__device__ __forceinline__ float dppmov(float x) {
    return __builtin_bit_cast(float,
        __builtin_amdgcn_update_dpp(0, __builtin_bit_cast(int, x), CTRL, 0xf, 0xf, true));
}
__device__ __forceinline__ float red16max(float x) {
    x = fmaxf(x, dppmov<0xB1>(x));   // quad_perm xor1
    x = fmaxf(x, dppmov<0x4E>(x));   // quad_perm xor2
    x = fmaxf(x, dppmov<0x141>(x));  // row_half_mirror
    x = fmaxf(x, dppmov<0x140>(x));  // row_mirror
    return x;
}
__device__ __forceinline__ float red16sum(float x) {
    x += dppmov<0xB1>(x);
    x += dppmov<0x4E>(x);
    x += dppmov<0x141>(x);
    x += dppmov<0x140>(x);
    return x;
}

// ---------------------------------------------------------------------------
// Fused prep: weight transposes (fp32->bf16) + x fp32->bf16 convert.
// grid (160, 32): bx<96 wq-transpose; 96<=bx<128 wo-transpose; bx>=128 cvt.
// ---------------------------------------------------------------------------
__global__ __launch_bounds__(256) void prep_kernel(
    const float* __restrict__ wq, const float* __restrict__ wo,
    const float* __restrict__ x,
    __hip_bfloat16* __restrict__ wqT, __hip_bfloat16* __restrict__ woT,
    __hip_bfloat16* __restrict__ xb) {
    const int t = threadIdx.x;
    const int bx = blockIdx.x;
    if (bx >= 128) {
        const size_t id = (size_t)(bx - 128) * 32 + blockIdx.y;   // 0..1023
        const size_t i  = id * 2048 + t * 8;
        float f[8]; __builtin_memcpy(f, x + i, 32);
        short8 v;
#pragma unroll
        for (int j = 0; j < 8; ++j) v[j] = bf16bits(f[j]);
        st8(xb + i, v);
        return;
    }
    __shared__ __hip_bfloat16 tile[32][33];
    const int tx = t % 32, ty = t / 32;
    const int r0 = blockIdx.y * 32;
    const float* src; __hip_bfloat16* dst; int ss, ds, c0;
    if (bx < 96) { src = wq; dst = wqT; ss = 3 * DM; ds = DM; c0 = bx * 32; }
    else         { src = wo; dst = woT; ss = DM;     ds = DM; c0 = (bx - 96) * 32; }
#pragma unroll
    for (int i = 0; i < 4; ++i)
        tile[ty + i * 8][tx] = __float2bfloat16(src[(size_t)(r0 + ty + i * 8) * ss + c0 + tx]);
    __syncthreads();
#pragma unroll
    for (int i = 0; i < 4; ++i)
        dst[(size_t)(c0 + ty + i * 8) * ds + r0 + tx] = tile[tx][ty + i * 8];
}

// ---------------------------------------------------------------------------
// bf16 -> bf16 tiled transpose (for V^T).
// ---------------------------------------------------------------------------
__global__ __launch_bounds__(256) void transpose_v(
    const __hip_bfloat16* __restrict__ src, __hip_bfloat16* __restrict__ dst,
    int s_stride, int d_stride) {
    __shared__ __hip_bfloat16 tile[32][33];
    const int t = threadIdx.x;
    const int tx = t % 32, ty = t / 32;
    const int c0 = blockIdx.x * 32, r0 = blockIdx.y * 32;
#pragma unroll
    for (int i = 0; i < 4; ++i)
        tile[ty + i * 8][tx] = src[(size_t)(r0 + ty + i * 8) * s_stride + c0 + tx];
    __syncthreads();
#pragma unroll
    for (int i = 0; i < 4; ++i)
        dst[(size_t)(c0 + ty + i * 8) * d_stride + r0 + tx] = tile[tx][ty + i * 8];
}

// ---------------------------------------------------------------------------
// bf16 MFMA GEMM, 128x(32*NT)x32 tiles, 4 waves (2x2), global_load_lds.
// NT=2 -> 128x64 tile (768 blocks for GEMM1 = 3/CU).
// ---------------------------------------------------------------------------
template <int NT, typename TC>
__global__ __launch_bounds__(256) void gemm_mfma(
    const __hip_bfloat16* __restrict__ A,
    const __hip_bfloat16* __restrict__ BT,
    TC* __restrict__ C,
    int M, int N, int K) {
    __shared__ short As[128 * 32];
    __shared__ short Bs[32 * NT * 32];

    const int t = threadIdx.x;
    const int w = t >> 6, lane = t & 63;
    const int l15 = lane & 15, quad = lane >> 4;
    const int row0 = blockIdx.y * 128;
    const int col0 = blockIdx.x * (32 * NT);
    const int wm = w >> 1, wn = w & 1;

    float4v acc[4][NT];
#pragma unroll
    for (int i = 0; i < 4; ++i)
#pragma unroll
        for (int j = 0; j < NT; ++j) acc[i][j] = (float4v){0.f, 0.f, 0.f, 0.f};

    const int mloc0 = lane >> 2;
    const int u     = lane & 3;

    for (int k0 = 0; k0 < K; k0 += 32) {
#pragma unroll
        for (int i = 0; i < 2; ++i) {
            const int c = 2 * w + i;
            async16(&As[c * 512], A + (size_t)(row0 + c * 16 + mloc0) * K + k0 + u * 8);
        }
#pragma unroll
        for (int i = 0; i < NT / 2; ++i) {
            const int c = (NT / 2) * w + i;
            async16(&Bs[c * 512], BT + (size_t)(col0 + c * 16 + mloc0) * K + k0 + u * 8);
        }
        __syncthreads();

        short8 af[4], bf[NT];
#pragma unroll
        for (int mt = 0; mt < 4; ++mt)
            af[mt] = ld8(&As[(wm * 64 + mt * 16 + l15) * 32 + quad * 8]);
#pragma unroll
        for (int nt = 0; nt < NT; ++nt)
            bf[nt] = ld8(&Bs[(wn * 16 * NT + nt * 16 + l15) * 32 + quad * 8]);
#pragma unroll
        for (int mt = 0; mt < 4; ++mt)
#pragma unroll
            for (int nt = 0; nt < NT; ++nt)
                acc[mt][nt] = __builtin_amdgcn_mfma_f32_16x16x32_bf16(
                    af[mt], bf[nt], acc[mt][nt], 0, 0, 0);
        __syncthreads();
    }

#pragma unroll
    for (int mt = 0; mt < 4; ++mt)
#pragma unroll
        for (int nt = 0; nt < NT; ++nt)
#pragma unroll
            for (int r = 0; r < 4; ++r) {
                const int row = row0 + wm * 64 + mt * 16 + quad * 4 + r;
                const int col = col0 + wn * 16 * NT + nt * 16 + l15;
                float v = acc[mt][nt][r];
                if constexpr (__is_same(TC, float)) C[(size_t)row * N + col] = v;
                else C[(size_t)row * N + col] = __float2bfloat16(v);
            }
}

// ---------------------------------------------------------------------------
// 64x64-tile GEMM (4 waves 2x2, each 32x32) — for GEMM3: 512 blocks = 2/CU.
// ---------------------------------------------------------------------------
__global__ __launch_bounds__(256) void gemm64(
    const __hip_bfloat16* __restrict__ A,
    const __hip_bfloat16* __restrict__ BT,
    float* __restrict__ C,
    int M, int N, int K) {
    __shared__ short As[64 * 32];
    __shared__ short Bs[64 * 32];

    const int t = threadIdx.x;
    const int w = t >> 6, lane = t & 63;
    const int l15 = lane & 15, quad = lane >> 4;
    const int row0 = blockIdx.y * 64;
    const int col0 = blockIdx.x * 64;
    const int wm = w >> 1, wn = w & 1;

    float4v acc[2][2];
#pragma unroll
    for (int i = 0; i < 2; ++i)
#pragma unroll
        for (int j = 0; j < 2; ++j) acc[i][j] = (float4v){0.f, 0.f, 0.f, 0.f};

    const int mloc0 = lane >> 2;
    const int u     = lane & 3;

    for (int k0 = 0; k0 < K; k0 += 32) {
        async16(&As[w * 512], A  + (size_t)(row0 + w * 16 + mloc0) * K + k0 + u * 8);
        async16(&Bs[w * 512], BT + (size_t)(col0 + w * 16 + mloc0) * K + k0 + u * 8);
        __syncthreads();

        short8 af[2], bf[2];
#pragma unroll
        for (int mt = 0; mt < 2; ++mt)
            af[mt] = ld8(&As[(wm * 32 + mt * 16 + l15) * 32 + quad * 8]);
#pragma unroll
        for (int nt = 0; nt < 2; ++nt)
            bf[nt] = ld8(&Bs[(wn * 32 + nt * 16 + l15) * 32 + quad * 8]);
#pragma unroll
        for (int mt = 0; mt < 2; ++mt)
#pragma unroll
            for (int nt = 0; nt < 2; ++nt)
                acc[mt][nt] = __builtin_amdgcn_mfma_f32_16x16x32_bf16(
                    af[mt], bf[nt], acc[mt][nt], 0, 0, 0);
        __syncthreads();
    }

#pragma unroll
    for (int mt = 0; mt < 2; ++mt)
#pragma unroll
        for (int nt = 0; nt < 2; ++nt)
#pragma unroll
            for (int r = 0; r < 4; ++r) {
                const int row = row0 + wm * 32 + mt * 16 + quad * 4 + r;
                const int col = col0 + wn * 32 + nt * 16 + l15;
                C[(size_t)row * N + col] = acc[mt][nt][r];
            }
}

// ---------------------------------------------------------------------------
// MFMA flash attention, 128-key tiles, DPP softmax, uniform-bias fast path.
// Vt/Pl stride 132 shorts (66 dwords = 2 mod 32: measured-clean bank class).
// ---------------------------------------------------------------------------
#define TK  128   // keys per iteration
#define KS  68    // Kt row stride (shorts), 34 dwords
#define VS  132   // Vt / Pl row stride (shorts), 66 dwords

__global__ __launch_bounds__(256) void attn_mfma(
    const __hip_bfloat16* __restrict__ qkv,
    const __hip_bfloat16* __restrict__ vT,
    const float* __restrict__ rel_bias,
    __hip_bfloat16* __restrict__ attnb) {
    __shared__ short Kt[TK * KS];        // [key][d]
    __shared__ short Vt[DH * VS];        // [d][key]
    __shared__ short Pl[4 * 16 * VS];    // per-wave P [q][key]
    __shared__ float biasL[MAXD];

    const int t = threadIdx.x;
    const int w = t >> 6, lane = t & 63;
    const int l15 = lane & 15, quad = lane >> 4;
    const int h  = blockIdx.y;
    const int q0 = blockIdx.x * 64;
    const int qw = q0 + w * 16;

    if (t < MAXD) biasL[t] = rel_bias[t * NH + h];

    // persistent Q fragments, pre-scaled by 0.125 (exact in bf16)
    short8 qf[2];
#pragma unroll
    for (int c = 0; c < 2; ++c) {
        short8 raw = ld8(qkv + (size_t)(qw + l15) * (3 * DM) + h * DH + c * 32 + quad * 8);
#pragma unroll
        for (int j = 0; j < 8; ++j) qf[c][j] = bf16bits(bits2f(raw[j]) * 0.125f);
    }

    float4v o_acc[4];
#pragma unroll
    for (int nt = 0; nt < 4; ++nt) o_acc[nt] = (float4v){0.f, 0.f, 0.f, 0.f};
    float m_i[4], l_i[4];
#pragma unroll
    for (int r = 0; r < 4; ++r) { m_i[r] = -1e30f; l_i[r] = 0.f; }

    for (int kb = 0; kb < SEQ / TK; ++kb) {
        const int k0 = kb * TK;
#pragma unroll
        for (int p = 0; p < 4; ++p) {
            const int idx = p * 256 + t;
            const int row = idx >> 3, u = idx & 7;
            st8(&Kt[row * KS + u * 8],
                ld8(qkv + (size_t)(k0 + row) * (3 * DM) + DM + h * DH + u * 8));
        }
#pragma unroll
        for (int p = 0; p < 4; ++p) {
            const int idx = p * 256 + t;
            const int row = idx >> 4, u = idx & 15;
            st8(&Vt[row * VS + u * 8],
                ld8(vT + (size_t)(h * DH + row) * SEQ + k0 + u * 8));
        }
        __syncthreads();

        // S = Q K^T : 8 key-blocks of 16
        float4v s_acc[8];
#pragma unroll
        for (int kt = 0; kt < 8; ++kt) s_acc[kt] = (float4v){0.f, 0.f, 0.f, 0.f};
#pragma unroll
        for (int c = 0; c < 2; ++c)
#pragma unroll
            for (int kt = 0; kt < 8; ++kt) {
                short8 kf = ld8(&Kt[(kt * 16 + l15) * KS + (c * 4 + quad) * 8]);
                s_acc[kt] = __builtin_amdgcn_mfma_f32_16x16x32_bf16(qf[c], kf, s_acc[kt], 0, 0, 0);
            }

        // bias (wave-uniform fast path when whole tile is at max distance)
        float sv[8][4];
        const int dlo = k0 - (qw + 15);
        const int dhi = qw - (k0 + TK - 1);
        if (dlo >= MAXD - 1 || dhi >= MAXD - 1) {
            const float bu = biasL[MAXD - 1];
#pragma unroll
            for (int kt = 0; kt < 8; ++kt)
#pragma unroll
                for (int r = 0; r < 4; ++r) sv[kt][r] = s_acc[kt][r] + bu;
        } else {
#pragma unroll
            for (int kt = 0; kt < 8; ++kt)
#pragma unroll
                for (int r = 0; r < 4; ++r) {
                    const int kg = k0 + kt * 16 + l15;
                    const int qg = qw + quad * 4 + r;
                    int rel = kg - qg; if (rel < 0) rel = -rel;
                    if (rel > MAXD - 1) rel = MAXD - 1;
                    sv[kt][r] = s_acc[kt][r] + biasL[rel];
                }
        }

        // online softmax (DPP reductions across the 16 lanes of each quad-row)
        float rowm[4];
#pragma unroll
        for (int r = 0; r < 4; ++r) {
            float m = sv[0][r];
#pragma unroll
            for (int kt = 1; kt < 8; ++kt) m = fmaxf(m, sv[kt][r]);
            rowm[r] = red16max(m);
        }

        float al[4], rs[4];
#pragma unroll
        for (int r = 0; r < 4; ++r) {
            const float mn = fmaxf(m_i[r], rowm[r]);
            al[r] = __expf(m_i[r] - mn);
            m_i[r] = mn;
            rs[r] = 0.f;
        }
#pragma unroll
        for (int kt = 0; kt < 8; ++kt)
#pragma unroll
            for (int r = 0; r < 4; ++r) {
                const float p = __expf(sv[kt][r] - m_i[r]);
                sv[kt][r] = p;
                rs[r] += p;
            }
#pragma unroll
        for (int r = 0; r < 4; ++r) {
            rs[r] = red16sum(rs[r]);
            l_i[r] = l_i[r] * al[r] + rs[r];
        }
#pragma unroll
        for (int nt = 0; nt < 4; ++nt)
#pragma unroll
            for (int r = 0; r < 4; ++r) o_acc[nt][r] *= al[r];

        // P -> per-wave LDS ([q][key], stride VS)
#pragma unroll
        for (int kt = 0; kt < 8; ++kt)
#pragma unroll
            for (int r = 0; r < 4; ++r)
                Pl[w * 16 * VS + (quad * 4 + r) * VS + kt * 16 + l15] = bf16bits(sv[kt][r]);

        // O += P V
#pragma unroll
        for (int kc = 0; kc < 4; ++kc) {
            short8 pf = ld8(&Pl[w * 16 * VS + l15 * VS + kc * 32 + quad * 8]);
#pragma unroll
            for (int nt = 0; nt < 4; ++nt) {
                short8 vf = ld8(&Vt[(nt * 16 + l15) * VS + kc * 32 + quad * 8]);
                o_acc[nt] = __builtin_amdgcn_mfma_f32_16x16x32_bf16(pf, vf, o_acc[nt], 0, 0, 0);
            }
        }
        __syncthreads();
    }

    // normalize + store
#pragma unroll
    for (int nt = 0; nt < 4; ++nt)
#pragma unroll
        for (int r = 0; r < 4; ++r) {
            const int row = qw + quad * 4 + r;
            const int col = h * DH + nt * 16 + l15;
            attnb[(size_t)row * DM + col] = __float2bfloat16(o_acc[nt][r] / l_i[r]);
        }
}

extern "C" void kernel_launch(void* const* d_in, const int* in_sizes, int n_in,
                              void* d_out, int out_size, void* d_ws, size_t ws_size,
                              hipStream_t stream) {
    const float* x        = (const float*)d_in[0];
    const float* w_qkv    = (const float*)d_in[1];
    const float* w_out    = (const float*)d_in[2];
    const float* rel_bias = (const float*)d_in[3];
    float* out = (float*)d_out;

    // ws layout (16-B aligned)
    char* p = (char*)d_ws;
    __hip_bfloat16* xb    = (__hip_bfloat16*)p;  p += (size_t)SEQ * DM * 2;      // 4 MB
    __hip_bfloat16* wqT   = (__hip_bfloat16*)p;  p += (size_t)3 * DM * DM * 2;   // 6 MB
    __hip_bfloat16* woT   = (__hip_bfloat16*)p;  p += (size_t)DM * DM * 2;       // 2 MB
    __hip_bfloat16* qkvb  = (__hip_bfloat16*)p;  p += (size_t)SEQ * 3 * DM * 2;  // 12 MB
    __hip_bfloat16* vT    = (__hip_bfloat16*)p;  p += (size_t)DM * SEQ * 2;      // 4 MB
    __hip_bfloat16* attnb = (__hip_bfloat16*)p;                                  // 4 MB

    // prep: weight transposes + x->bf16 (one launch)
    prep_kernel<<<dim3(160, 32), 256, 0, stream>>>(w_qkv, w_out, x, wqT, woT, xb);

    // 1) qkv = x @ w_qkv   (128x64 tiles, 768 blocks = 3/CU)
    gemm_mfma<2, __hip_bfloat16><<<dim3(3 * DM / 64, SEQ / 128), 256, 0, stream>>>(
        xb, wqT, qkvb, SEQ, 3 * DM, DM);

    // V^T for attention B-frags
    transpose_v<<<dim3(DM / 32, SEQ / 32), 256, 0, stream>>>(
        qkvb + 2 * DM, vT, 3 * DM, SEQ);

    // 2) attention
    attn_mfma<<<dim3(SEQ / 64, NH), 256, 0, stream>>>(qkvb, vT, rel_bias, attnb);

    // 3) out = attn @ w_out  (64x64 tiles, 512 blocks = 2/CU)
    gemm64<<<dim3(DM / 64, SEQ / 64), 256, 0, stream>>>(
        attnb, woT, out, SEQ, DM, DM);
}